// Round 1
// baseline (293.264 us; speedup 1.0000x reference)
//
#include <hip/hip_runtime.h>
#include <math.h>

// Problem: mean over B rows of KL divergence between diagonal Gaussians.
// B=65536, N=256. out = 0.5 * (sum_all_elems(term) / B - N), where
// term = log(s2) - log(s1) + s1/s2 + (mask*(mu2-mu1))^2 / s2.
// Memory-bound: 320 MiB read -> ~53us floor at 6.3 TB/s.

constexpr int B_ROWS = 65536;
constexpr int N_COLS = 256;
constexpr int TOTAL4 = (B_ROWS * N_COLS) / 4;  // 4,194,304 float4s per array
constexpr int GRID1  = 2048;                   // 8 blocks/CU on 256 CUs
constexpr int BLOCK  = 256;

__device__ __forceinline__ float kl_term(float m1, float m2, float s1, float s2, float mk) {
    // reference applies nan_to_num(mu1, nan=0.0)
    m1 = __builtin_isnan(m1) ? 0.0f : m1;
    float d  = mk * (m2 - m1);
    float r2 = __builtin_amdgcn_rcpf(s2);          // ~1 ulp approx; tolerance is 2%
    // log(s2) - log(s1) = ln2 * (log2(s2) - log2(s1)); v_log_f32 is log2
    float lg = 0.69314718055994531f * (__log2f(s2) - __log2f(s1));
    return lg + (s1 + d * d) * r2;                 // term1 + term2 + term3 components
}

__global__ __launch_bounds__(BLOCK) void kl_partial_kernel(
    const float4* __restrict__ mu1, const float4* __restrict__ mu2,
    const float4* __restrict__ s1,  const float4* __restrict__ s2,
    const float4* __restrict__ mask, float* __restrict__ partials)
{
    float acc = 0.0f;
    const int stride = GRID1 * BLOCK;
    for (int i = blockIdx.x * BLOCK + threadIdx.x; i < TOTAL4; i += stride) {
        float4 a = mu1[i];
        float4 b = mu2[i];
        float4 p = s1[i];
        float4 q = s2[i];
        float4 m = mask[i];
        acc += kl_term(a.x, b.x, p.x, q.x, m.x);
        acc += kl_term(a.y, b.y, p.y, q.y, m.y);
        acc += kl_term(a.z, b.z, p.z, q.z, m.z);
        acc += kl_term(a.w, b.w, p.w, q.w, m.w);
    }
    // wave-64 butterfly-free down-shuffle reduction
    #pragma unroll
    for (int off = 32; off > 0; off >>= 1) acc += __shfl_down(acc, off, 64);
    __shared__ float wsum[BLOCK / 64];
    const int lane = threadIdx.x & 63;
    const int wv   = threadIdx.x >> 6;
    if (lane == 0) wsum[wv] = acc;
    __syncthreads();
    if (threadIdx.x == 0) {
        float s = 0.0f;
        #pragma unroll
        for (int w = 0; w < BLOCK / 64; ++w) s += wsum[w];
        partials[blockIdx.x] = s;  // written unconditionally every launch: 0xAA poison safe
    }
}

__global__ __launch_bounds__(BLOCK) void kl_final_kernel(
    const float* __restrict__ partials, float* __restrict__ out)
{
    double acc = 0.0;
    for (int i = threadIdx.x; i < GRID1; i += BLOCK) acc += (double)partials[i];
    #pragma unroll
    for (int off = 32; off > 0; off >>= 1) acc += __shfl_down(acc, off, 64);
    __shared__ double wsum[BLOCK / 64];
    const int lane = threadIdx.x & 63;
    const int wv   = threadIdx.x >> 6;
    if (lane == 0) wsum[wv] = acc;
    __syncthreads();
    if (threadIdx.x == 0) {
        double s = 0.0;
        #pragma unroll
        for (int w = 0; w < BLOCK / 64; ++w) s += wsum[w];
        out[0] = (float)(0.5 * s / (double)B_ROWS - 0.5 * (double)N_COLS);
    }
}

extern "C" void kernel_launch(void* const* d_in, const int* in_sizes, int n_in,
                              void* d_out, int out_size, void* d_ws, size_t ws_size,
                              hipStream_t stream) {
    const float4* mu1  = (const float4*)d_in[0];
    const float4* mu2  = (const float4*)d_in[1];
    const float4* sg1  = (const float4*)d_in[2];
    const float4* sg2  = (const float4*)d_in[3];
    const float4* mask = (const float4*)d_in[4];
    float* partials = (float*)d_ws;  // GRID1 floats = 8 KiB scratch
    float* out = (float*)d_out;

    kl_partial_kernel<<<GRID1, BLOCK, 0, stream>>>(mu1, mu2, sg1, sg2, mask, partials);
    kl_final_kernel<<<1, BLOCK, 0, stream>>>(partials, out);
}

// Round 2
// 291.636 us; speedup vs baseline: 1.0056x; 1.0056x over previous
//
#include <hip/hip_runtime.h>
#include <math.h>

// Mean over B rows of KL divergence between diagonal Gaussians.
// B=65536, N=256. out = 0.5 * (sum_all(term)/B - N), where
// term = log(s2)-log(s1) + s1/s2 + (mask*(mu2-mu1))^2/s2.
//
// R1 post-mortem: latency-bound (113us, 18% HBM, VALU 5%, VGPR=20 ->
// only 5 loads in flight/wave, grid-stride 8MiB jumps). R2: contiguous
// per-block tiles + fully unrolled loop so the compiler pipelines many
// independent loads per wave.

constexpr int B_ROWS = 65536;
constexpr int N_COLS = 256;
constexpr int TOTAL4 = (B_ROWS * N_COLS) / 4;  // 4,194,304 float4s per array
constexpr int GRID1  = 2048;                   // 8 blocks/CU
constexpr int BLOCK  = 256;
constexpr int PER_BLOCK4 = TOTAL4 / GRID1;     // 2048 float4s (32 KiB/array)
constexpr int ITERS  = PER_BLOCK4 / BLOCK;     // 8 float4s per thread per array

__device__ __forceinline__ float kl_term(float m1, float m2, float s1, float s2, float mk) {
    m1 = __builtin_isnan(m1) ? 0.0f : m1;      // nan_to_num(mu1)
    float d  = mk * (m2 - m1);
    float r2 = __builtin_amdgcn_rcpf(s2);      // tolerance is 2%; approx ok
    float lg = 0.69314718055994531f * (__log2f(s2) - __log2f(s1));
    return lg + (s1 + d * d) * r2;
}

__device__ __forceinline__ float kl4(float4 a, float4 b, float4 p, float4 q, float4 m) {
    return kl_term(a.x, b.x, p.x, q.x, m.x)
         + kl_term(a.y, b.y, p.y, q.y, m.y)
         + kl_term(a.z, b.z, p.z, q.z, m.z)
         + kl_term(a.w, b.w, p.w, q.w, m.w);
}

__global__ __launch_bounds__(BLOCK) void kl_partial_kernel(
    const float4* __restrict__ mu1, const float4* __restrict__ mu2,
    const float4* __restrict__ s1,  const float4* __restrict__ s2,
    const float4* __restrict__ mask, float* __restrict__ partials)
{
    // Block-contiguous tile: block owns [blockIdx.x*2048, +2048) float4s.
    const int base = blockIdx.x * PER_BLOCK4 + threadIdx.x;

    // Fully unrolled with independent addresses -> compiler can hoist /
    // software-pipeline many loads (raises in-flight bytes per wave).
    float partial[ITERS];
    #pragma unroll
    for (int k = 0; k < ITERS; ++k) {
        const int i = base + k * BLOCK;
        float4 a = mu1[i];
        float4 b = mu2[i];
        float4 p = s1[i];
        float4 q = s2[i];
        float4 m = mask[i];
        partial[k] = kl4(a, b, p, q, m);
    }
    float acc = 0.0f;
    #pragma unroll
    for (int k = 0; k < ITERS; ++k) acc += partial[k];

    // wave-64 reduction
    #pragma unroll
    for (int off = 32; off > 0; off >>= 1) acc += __shfl_down(acc, off, 64);
    __shared__ float wsum[BLOCK / 64];
    const int lane = threadIdx.x & 63;
    const int wv   = threadIdx.x >> 6;
    if (lane == 0) wsum[wv] = acc;
    __syncthreads();
    if (threadIdx.x == 0) {
        float s = 0.0f;
        #pragma unroll
        for (int w = 0; w < BLOCK / 64; ++w) s += wsum[w];
        partials[blockIdx.x] = s;  // unconditional write every launch (poison-safe)
    }
}

__global__ __launch_bounds__(BLOCK) void kl_final_kernel(
    const float* __restrict__ partials, float* __restrict__ out)
{
    double acc = 0.0;
    for (int i = threadIdx.x; i < GRID1; i += BLOCK) acc += (double)partials[i];
    #pragma unroll
    for (int off = 32; off > 0; off >>= 1) acc += __shfl_down(acc, off, 64);
    __shared__ double wsum[BLOCK / 64];
    const int lane = threadIdx.x & 63;
    const int wv   = threadIdx.x >> 6;
    if (lane == 0) wsum[wv] = acc;
    __syncthreads();
    if (threadIdx.x == 0) {
        double s = 0.0;
        #pragma unroll
        for (int w = 0; w < BLOCK / 64; ++w) s += wsum[w];
        out[0] = (float)(0.5 * s / (double)B_ROWS - 0.5 * (double)N_COLS);
    }
}

extern "C" void kernel_launch(void* const* d_in, const int* in_sizes, int n_in,
                              void* d_out, int out_size, void* d_ws, size_t ws_size,
                              hipStream_t stream) {
    const float4* mu1  = (const float4*)d_in[0];
    const float4* mu2  = (const float4*)d_in[1];
    const float4* sg1  = (const float4*)d_in[2];
    const float4* sg2  = (const float4*)d_in[3];
    const float4* mask = (const float4*)d_in[4];
    float* partials = (float*)d_ws;  // GRID1 floats = 8 KiB scratch
    float* out = (float*)d_out;

    kl_partial_kernel<<<GRID1, BLOCK, 0, stream>>>(mu1, mu2, sg1, sg2, mask, partials);
    kl_final_kernel<<<1, BLOCK, 0, stream>>>(partials, out);
}